// Round 10
// baseline (135.059 us; speedup 1.0000x reference)
//
#include <hip/hip_runtime.h>
#include <math.h>

// Problem constants
#define NB    32
#define NHEAD 16
#define HW    1024

typedef float f32x4  __attribute__((ext_vector_type(4)));
typedef short bf16x2 __attribute__((ext_vector_type(2)));
typedef short bf16x4 __attribute__((ext_vector_type(4)));
typedef short bf16x8 __attribute__((ext_vector_type(8)));

__device__ __forceinline__ short f2bf(float f) {   // fp32 -> bf16 RNE
    union { float f; unsigned u; } c; c.f = f;
    unsigned r = c.u + 0x7FFFu + ((c.u >> 16) & 1u);
    return (short)(r >> 16);
}
#define SWZ(row) ((((row) >> 1) & 7) << 4)   // legacy (queryqk)
#define SWX(x)   ((((x) >> 2) & 7) << 4)     // fx image key
#define SWI(i)   ((((i) & 7)) << 4)          // fi image key
#define SWL(l)   ((((l) & 7)) << 4)          // fcn/wv key
#define MFMA16(a, b, c) __builtin_amdgcn_mfma_f32_16x16x32_bf16(a, b, c, 0, 0, 0)

__device__ __forceinline__ bf16x8 lds_ld8(const short* base, int off) {
    return *(const bf16x8*)((const char*)base + off);
}
__device__ __forceinline__ void lds_st4(short* base, int off, bf16x4 v) {
    *(bf16x4*)((char*)base + off) = v;
}

// ---------------------------------------------------------------------------
// Kernel 0: prep — bf16 casts / transposes / bias fold. (unchanged, passes)
// ---------------------------------------------------------------------------
__global__ __launch_bounds__(256) void prep_kernel(
        const float* __restrict__ Wq, const float* __restrict__ token,
        const float* __restrict__ Wk, const float* __restrict__ bq,
        short* __restrict__ Wq_bf, short* __restrict__ tok_t,
        short* __restrict__ Wk_t, float* __restrict__ qkb) {
    __shared__ float red[256];
    const int b = blockIdx.x, t = threadIdx.x;
    if (b < 1024) {
        const size_t idx = (size_t)b * 1024 + t * 4;
        const f32x4 v = *(const f32x4*)(Wq + idx);
        bf16x4 o; o[0]=f2bf(v[0]); o[1]=f2bf(v[1]); o[2]=f2bf(v[2]); o[3]=f2bf(v[3]);
        *(bf16x4*)(Wq_bf + idx) = o;
    } else if (b < 1056) {
        const int n = b - 1024;
        const int c0 = t * 4;
        float arr[4][16];
#pragma unroll
        for (int ci = 0; ci < 4; ++ci)
#pragma unroll
            for (int lq = 0; lq < 4; ++lq) {
                const f32x4 v = *(const f32x4*)(token + (size_t)n*16384 + (size_t)(c0+ci)*16 + lq*4);
#pragma unroll
                for (int e = 0; e < 4; ++e) arr[ci][lq*4+e] = v[e];
            }
#pragma unroll
        for (int l = 0; l < 16; ++l) {
            bf16x4 o; o[0]=f2bf(arr[0][l]); o[1]=f2bf(arr[1][l]); o[2]=f2bf(arr[2][l]); o[3]=f2bf(arr[3][l]);
            *(bf16x4*)(tok_t + (size_t)n*16384 + (size_t)l*1024 + c0) = o;
        }
    } else {
        const int h = b - 1056;
        const int i = t & 63, dq = t >> 6;
        float qs = 0.f; short wt[16];
#pragma unroll
        for (int k = 0; k < 16; ++k) {
            const int d = dq*16 + k;
            const float wv = Wk[(size_t)h*4096 + d*64 + i];
            qs += wv * bq[h*64 + d];
            wt[k] = f2bf(wv);
        }
#pragma unroll
        for (int kq = 0; kq < 4; ++kq) {
            bf16x4 o; o[0]=wt[kq*4]; o[1]=wt[kq*4+1]; o[2]=wt[kq*4+2]; o[3]=wt[kq*4+3];
            *(bf16x4*)(Wk_t + (size_t)h*4096 + i*64 + dq*16 + kq*4) = o;
        }
        red[t] = qs;
        __syncthreads();
        if (t < 64)
            qkb[h*64 + t] = (red[t] + red[t+64] + red[t+128] + red[t+192]) * 0.125f;
    }
}

// ---------------------------------------------------------------------------
// Kernel 1: fused query + qk (all-MFMA). (unchanged, passes)
// Output qk_bf layout: [nh][l][i] (row l, 64 i contiguous).
// ---------------------------------------------------------------------------
__global__ __launch_bounds__(256) void queryqk_kernel(
        const short* __restrict__ Wq_bf, const short* __restrict__ tok_t,
        const short* __restrict__ Wk_t, const float* __restrict__ qkb,
        short* __restrict__ qk_bf) {
    __shared__ short q_ld[16 * 64];
    const int t = threadIdx.x, w = t >> 6, L = t & 63;
    const int lr = L & 15, hg = L >> 4;
    const int nh = blockIdx.x, n = nh >> 4, h = nh & 15;

    f32x4 acc = {0.f, 0.f, 0.f, 0.f};
    const short* aA = Wq_bf + (size_t)(h*64 + w*16 + lr) * 1024 + hg*8;
    const short* aB = tok_t + (size_t)n*16384 + (size_t)lr*1024 + hg*8;
#pragma unroll 4
    for (int ks = 0; ks < 32; ++ks) {
        const bf16x8 a = *(const bf16x8*)(aA + ks*32);
        const bf16x8 bb = *(const bf16x8*)(aB + ks*32);
        acc = MFMA16(a, bb, acc);
    }
    {
        bf16x4 qv; qv[0]=f2bf(acc[0]); qv[1]=f2bf(acc[1]); qv[2]=f2bf(acc[2]); qv[3]=f2bf(acc[3]);
        lds_st4(q_ld, (lr*128 + w*32 + hg*8) ^ SWZ(lr), qv);
    }
    __syncthreads();
    f32x4 a2 = {0.f, 0.f, 0.f, 0.f};
#pragma unroll
    for (int ks = 0; ks < 2; ++ks) {
        const bf16x8 a = *(const bf16x8*)(Wk_t + (size_t)h*4096 + (w*16 + lr)*64 + ks*32 + hg*8);
        const bf16x8 bb = lds_ld8(q_ld, (lr*128 + ks*64 + hg*16) ^ SWZ(lr));
        a2 = MFMA16(a, bb, a2);
    }
    const int i0 = w*16 + hg*4;
    bf16x4 qk4;
#pragma unroll
    for (int r = 0; r < 4; ++r)
        qk4[r] = f2bf(a2[r] * 0.125f + qkb[h*64 + i0 + r]);
    *(bf16x4*)(qk_bf + (size_t)nh*1024 + lr*64 + i0) = qk4;
}

// ---------------------------------------------------------------------------
// Kernel 2: swapped-operand single-pass attention. 512 blocks x 512 threads
// (8 waves), LDS 77 KB -> 2 blocks/CU at VGPR cap 128.  Sibling block fills
// barrier gaps.  R9 bug fixed: fx staging now applies the XOR swizzle to the
// FULL byte offset ((x*128 + i*2) ^ SWX(x)); R9 XORed only the row base and
// ADDED the i-offset, carrying into neighbor rows -> clobbered image -> NaN.
//   S^T = qk^T @ f    (A = qk^T[l][i] from global, B = f from fx [x][i] image)
//   per-wave online softmax over its DISJOINT 32-x window per chunk
//   fc^T = P^T @ f    (A = P^T from per-wave scratch, B = f from fi [i][x] image)
//   final: cross-wave m/Z merge + rescale, reduce, Wv epilogue.
// ---------------------------------------------------------------------------
__global__ __launch_bounds__(512, 4) void attn_kernel(
        const float* __restrict__ feat, const short* __restrict__ qk_bf,
        const float* __restrict__ Wv, const float* __restrict__ bv,
        float* __restrict__ out0, float* __restrict__ out1) {
    __shared__ __align__(16) short fx[256 * 64];   // 32 KB [x256][i64] pitch 128B ^SWX(x); reused: f32 partial dump
    __shared__ __align__(16) short fi[64 * 256];   // 32 KB [i64][x256] pitch 512B ^SWI(i); reused: wv [d][i]
    __shared__ __align__(16) short p_scr[8 * 640]; // 10 KB per-wave [l16][x32] pitch 80B
    __shared__ __align__(16) short fcn[16 * 64];   // 2 KB [l][i] pitch 128B ^SWL(l)
    __shared__ float red_m[128], red_z[128];       // [w8][l16]

    const int t = threadIdx.x, w = t >> 6, L = t & 63;
    const int lr = L & 15, hg = L >> 4;
    const int nh = blockIdx.x, n = nh >> 4, h = nh & 15;
    const size_t fbase = (size_t)n*1048576 + (size_t)h*65536;

    // A-operand for logits: qk^T rows l
    const bf16x8 qkA0 = *(const bf16x8*)(qk_bf + (size_t)nh*1024 + lr*64 + hg*8);
    const bf16x8 qkA1 = *(const bf16x8*)(qk_bf + (size_t)nh*1024 + lr*64 + 32 + hg*8);

    const int sx = (t & 63) * 4;   // x-local staging base (lane-major: coalesced)
    const int si = (t >> 6) * 8;   // i staging base (8 rows per wave)
    short* p_w = p_scr + w * 640;  // this wave's P scratch

    // chunk-0 loads
    f32x4 v[8];
#pragma unroll
    for (int k = 0; k < 8; ++k)
        v[k] = *(const f32x4*)(feat + fbase + (size_t)(si+k)*1024 + sx);

    f32x4 acc_fc[4];
#pragma unroll
    for (int ct = 0; ct < 4; ++ct) acc_fc[ct] = (f32x4){0.f,0.f,0.f,0.f};
    float mrun[4] = {-INFINITY,-INFINITY,-INFINITY,-INFINITY};
    float Zrun[4] = {0.f,0.f,0.f,0.f};

#pragma unroll
    for (int c = 0; c < 4; ++c) {
        // ---- stage phase: v -> out0 + both LDS images ----
        bf16x4 vb[8];
#pragma unroll
        for (int k = 0; k < 8; ++k) {
            vb[k][0]=f2bf(v[k][0]); vb[k][1]=f2bf(v[k][1]);
            vb[k][2]=f2bf(v[k][2]); vb[k][3]=f2bf(v[k][3]);
        }
#pragma unroll
        for (int k = 0; k < 8; ++k) {
            const size_t g = fbase + (size_t)(si+k)*1024 + c*256 + sx;
            *(f32x4*)(out0 + g) = v[k];                                    // passthrough
            lds_st4(fi, ((si+k)*512 + sx*2) ^ SWI(si+k), vb[k]);           // [i][x]
        }
#pragma unroll
        for (int j = 0; j < 4; ++j) {                                      // [x][i]
            const int x = sx + j;
#pragma unroll
            for (int kp = 0; kp < 4; ++kp) {
                const int i2 = si + 2*kp;
                bf16x2 pr; pr[0] = vb[2*kp][j]; pr[1] = vb[2*kp+1][j];
                *(bf16x2*)((char*)fx + ((x*128 + i2*2) ^ SWX(x))) = pr;    // FULL-offset XOR (R9 fix)
            }
        }
        __syncthreads();
        // ---- prefetch chunk c+1 (overlaps whole consume phase) ----
        if (c < 3) {
#pragma unroll
            for (int k = 0; k < 8; ++k)
                v[k] = *(const f32x4*)(feat + fbase + (size_t)(si+k)*1024 + (c+1)*256 + sx);
        }
        // ---- logits: S^T tiles for wave's 32-x window ----
        f32x4 ST0 = {0.f,0.f,0.f,0.f}, ST1 = {0.f,0.f,0.f,0.f};
        {
            const int xb0 = w*32 + lr, xb1 = w*32 + 16 + lr;
            ST0 = MFMA16(qkA0, lds_ld8(fx, (xb0*128 + hg*16)      ^ SWX(xb0)), ST0);
            ST0 = MFMA16(qkA1, lds_ld8(fx, (xb0*128 + 64 + hg*16) ^ SWX(xb0)), ST0);
            ST1 = MFMA16(qkA0, lds_ld8(fx, (xb1*128 + hg*16)      ^ SWX(xb1)), ST1);
            ST1 = MFMA16(qkA1, lds_ld8(fx, (xb1*128 + 64 + hg*16) ^ SWX(xb1)), ST1);
        }
        // ---- per-wave online softmax (rows l = hg*4+r, cols = its 32 x) ----
#pragma unroll
        for (int r = 0; r < 4; ++r) {
            float cm = fmaxf(ST0[r], ST1[r]);
#pragma unroll
            for (int msk = 8; msk >= 1; msk >>= 1)
                cm = fmaxf(cm, __shfl_xor(cm, msk));          // within 16-lane group
            const float mnew = fmaxf(mrun[r], cm);
            const float rs = __expf(mrun[r] - mnew);          // first chunk: 0
            const float p0 = __expf(ST0[r] - mnew);
            const float p1 = __expf(ST1[r] - mnew);
            const int row = (hg*4 + r) * 80;
            *(short*)((char*)p_w + row + lr*2)      = f2bf(p0);
            *(short*)((char*)p_w + row + 32 + lr*2) = f2bf(p1);
            float zc = p0 + p1;
#pragma unroll
            for (int msk = 8; msk >= 1; msk >>= 1)
                zc += __shfl_xor(zc, msk);
            Zrun[r] = Zrun[r] * rs + zc;
            mrun[r] = mnew;
#pragma unroll
            for (int ct = 0; ct < 4; ++ct) acc_fc[ct][r] *= rs;
        }
        // ---- fc^T += P^T @ f  (K = wave's 32 x) ----
        {
            const bf16x8 pA = lds_ld8(p_w, lr*80 + hg*16);
#pragma unroll
            for (int ct = 0; ct < 4; ++ct) {
                const int i = ct*16 + lr;
                const bf16x8 fB = lds_ld8(fi, (i*512 + w*64 + hg*16) ^ SWI(i));
                acc_fc[ct] = MFMA16(pA, fB, acc_fc[ct]);
            }
        }
        __syncthreads();
    }

    // ---- cross-wave merge ----
    if (lr == 0) {
#pragma unroll
        for (int r = 0; r < 4; ++r) {
            red_m[w*16 + hg*4 + r] = mrun[r];
            red_z[w*16 + hg*4 + r] = Zrun[r];
        }
    }
    __syncthreads();
    {   // stage Wv into fi-carve [d][i] (fi dead now); all 512 threads
        const int d = t >> 3, i0 = (t & 7) * 8;
        const f32x4 a = *(const f32x4*)(Wv + (size_t)h*4096 + d*64 + i0);
        const f32x4 b = *(const f32x4*)(Wv + (size_t)h*4096 + d*64 + i0 + 4);
        bf16x8 wb;
        wb[0]=f2bf(a[0]); wb[1]=f2bf(a[1]); wb[2]=f2bf(a[2]); wb[3]=f2bf(a[3]);
        wb[4]=f2bf(b[0]); wb[5]=f2bf(b[1]); wb[6]=f2bf(b[2]); wb[7]=f2bf(b[3]);
        *(bf16x8*)((char*)fi + ((d*128 + i0*2) ^ SWL(d))) = wb;
    }
    {   // rescale own partials by exp(m_w - m_g), dump to fx region (dead)
        float sc[4];
#pragma unroll
        for (int r = 0; r < 4; ++r) {
            const int l = hg*4 + r;
            float m = red_m[l];
#pragma unroll
            for (int wp = 1; wp < 8; ++wp) m = fmaxf(m, red_m[wp*16 + l]);
            sc[r] = __expf(mrun[r] - m);
        }
#pragma unroll
        for (int ct = 0; ct < 4; ++ct) {
#pragma unroll
            for (int r = 0; r < 4; ++r) acc_fc[ct][r] *= sc[r];
            *(f32x4*)((char*)fx + (w*4 + ct)*1024 + L*16) = acc_fc[ct];
        }
    }
    __syncthreads();
    if (w < 4) {   // reduce i-tile w over 8 wave-partials; normalize; -> fcn
        f32x4 s = (f32x4){0.f,0.f,0.f,0.f};
#pragma unroll
        for (int wp = 0; wp < 8; ++wp)
            s += *(const f32x4*)((const char*)fx + (wp*4 + w)*1024 + L*16);
#pragma unroll
        for (int r = 0; r < 4; ++r) {
            const int l = hg*4 + r;
            float m = red_m[l];
#pragma unroll
            for (int wp = 1; wp < 8; ++wp) m = fmaxf(m, red_m[wp*16 + l]);
            float Z = 0.f;
#pragma unroll
            for (int wp = 0; wp < 8; ++wp)
                Z += __expf(red_m[wp*16 + l] - m) * red_z[wp*16 + l];
            *(short*)((char*)fcn + ((l*128 + (w*16 + lr)*2) ^ SWL(l))) = f2bf(s[r] / Z);
        }
    }
    __syncthreads();
    if (w < 4) {   // tok[d][l] = Wv @ fcn + bv; wave w owns d-tile w
        f32x4 acc = (f32x4){0.f,0.f,0.f,0.f};
        const int dm = w*16 + lr;
#pragma unroll
        for (int ks = 0; ks < 2; ++ks) {
            const bf16x8 a = lds_ld8(fi,  (dm*128 + ks*64 + hg*16) ^ SWL(dm));
            const bf16x8 b = lds_ld8(fcn, (lr*128 + ks*64 + hg*16) ^ SWL(lr));
            acc = MFMA16(a, b, acc);
        }
#pragma unroll
        for (int r = 0; r < 4; ++r) {
            const int d = w*16 + hg*4 + r;
            out1[((size_t)n*1024 + h*64 + d)*16 + lr] = acc[r] + bv[h*64 + d];
        }
    }
}

// ---------------------------------------------------------------------------
extern "C" void kernel_launch(void* const* d_in, const int* in_sizes, int n_in,
                              void* d_out, int out_size, void* d_ws, size_t ws_size,
                              hipStream_t stream) {
    const float* feature = (const float*)d_in[0];
    const float* token   = (const float*)d_in[1];
    const float* Wq      = (const float*)d_in[2];
    const float* bq      = (const float*)d_in[3];
    const float* Wk      = (const float*)d_in[4];
    // d_in[5] = bk: provably unused (constant along softmax axis)
    const float* Wv      = (const float*)d_in[6];
    const float* bv      = (const float*)d_in[7];

    float* out0 = (float*)d_out;                      // feature passthrough
    float* out1 = out0 + (size_t)NB * 1024 * HW;      // tok [n][c][l]

    short* Wq_bf = (short*)d_ws;                               // 2 MB
    short* tok_t = Wq_bf + (size_t)1024 * 1024;                // 1 MB
    short* Wk_t  = tok_t + (size_t)NB * 16 * 1024;             // 128 KB
    short* qk_bf = Wk_t + (size_t)NHEAD * 64 * 64;             // 1 MB
    float* qkb   = (float*)(qk_bf + (size_t)NB * NHEAD * 1024);// 4 KB

    prep_kernel   <<<dim3(1072), 256, 0, stream>>>(Wq, token, Wk, bq, Wq_bf, tok_t, Wk_t, qkb);
    queryqk_kernel<<<dim3(NB * NHEAD), 256, 0, stream>>>(Wq_bf, tok_t, Wk_t, qkb, qk_bf);
    attn_kernel   <<<dim3(NB * NHEAD), 512, 0, stream>>>(feature, qk_bf, Wv, bv, out0, out1);
}

// Round 11
// 134.685 us; speedup vs baseline: 1.0028x; 1.0028x over previous
//
#include <hip/hip_runtime.h>
#include <math.h>

// Problem constants
#define NB    32
#define NHEAD 16
#define HW    1024

typedef float f32x4  __attribute__((ext_vector_type(4)));
typedef short bf16x2 __attribute__((ext_vector_type(2)));
typedef short bf16x4 __attribute__((ext_vector_type(4)));
typedef short bf16x8 __attribute__((ext_vector_type(8)));

__device__ __forceinline__ short f2bf(float f) {   // fp32 -> bf16 RNE
    union { float f; unsigned u; } c; c.f = f;
    unsigned r = c.u + 0x7FFFu + ((c.u >> 16) & 1u);
    return (short)(r >> 16);
}
#define SWZ(row) ((((row) >> 1) & 7) << 4)   // legacy (queryqk)
#define SWX(x)   ((((x) >> 2) & 7) << 4)     // fx image key
#define SWI(i)   ((((i) & 7)) << 4)          // fi image key
#define SWL(l)   ((((l) & 7)) << 4)          // fcn/wv key
#define MFMA16(a, b, c) __builtin_amdgcn_mfma_f32_16x16x32_bf16(a, b, c, 0, 0, 0)

__device__ __forceinline__ bf16x8 lds_ld8(const short* base, int off) {
    return *(const bf16x8*)((const char*)base + off);
}
__device__ __forceinline__ void lds_st4(short* base, int off, bf16x4 v) {
    *(bf16x4*)((char*)base + off) = v;
}

// ---------------------------------------------------------------------------
// Kernel 0: prep — bf16 casts / transposes / bias fold. (unchanged, passes)
// ---------------------------------------------------------------------------
__global__ __launch_bounds__(256) void prep_kernel(
        const float* __restrict__ Wq, const float* __restrict__ token,
        const float* __restrict__ Wk, const float* __restrict__ bq,
        short* __restrict__ Wq_bf, short* __restrict__ tok_t,
        short* __restrict__ Wk_t, float* __restrict__ qkb) {
    __shared__ float red[256];
    const int b = blockIdx.x, t = threadIdx.x;
    if (b < 1024) {
        const size_t idx = (size_t)b * 1024 + t * 4;
        const f32x4 v = *(const f32x4*)(Wq + idx);
        bf16x4 o; o[0]=f2bf(v[0]); o[1]=f2bf(v[1]); o[2]=f2bf(v[2]); o[3]=f2bf(v[3]);
        *(bf16x4*)(Wq_bf + idx) = o;
    } else if (b < 1056) {
        const int n = b - 1024;
        const int c0 = t * 4;
        float arr[4][16];
#pragma unroll
        for (int ci = 0; ci < 4; ++ci)
#pragma unroll
            for (int lq = 0; lq < 4; ++lq) {
                const f32x4 v = *(const f32x4*)(token + (size_t)n*16384 + (size_t)(c0+ci)*16 + lq*4);
#pragma unroll
                for (int e = 0; e < 4; ++e) arr[ci][lq*4+e] = v[e];
            }
#pragma unroll
        for (int l = 0; l < 16; ++l) {
            bf16x4 o; o[0]=f2bf(arr[0][l]); o[1]=f2bf(arr[1][l]); o[2]=f2bf(arr[2][l]); o[3]=f2bf(arr[3][l]);
            *(bf16x4*)(tok_t + (size_t)n*16384 + (size_t)l*1024 + c0) = o;
        }
    } else {
        const int h = b - 1056;
        const int i = t & 63, dq = t >> 6;
        float qs = 0.f; short wt[16];
#pragma unroll
        for (int k = 0; k < 16; ++k) {
            const int d = dq*16 + k;
            const float wv = Wk[(size_t)h*4096 + d*64 + i];
            qs += wv * bq[h*64 + d];
            wt[k] = f2bf(wv);
        }
#pragma unroll
        for (int kq = 0; kq < 4; ++kq) {
            bf16x4 o; o[0]=wt[kq*4]; o[1]=wt[kq*4+1]; o[2]=wt[kq*4+2]; o[3]=wt[kq*4+3];
            *(bf16x4*)(Wk_t + (size_t)h*4096 + i*64 + dq*16 + kq*4) = o;
        }
        red[t] = qs;
        __syncthreads();
        if (t < 64)
            qkb[h*64 + t] = (red[t] + red[t+64] + red[t+128] + red[t+192]) * 0.125f;
    }
}

// ---------------------------------------------------------------------------
// Kernel 1: fused query + qk (all-MFMA). (unchanged, passes)
// ---------------------------------------------------------------------------
__global__ __launch_bounds__(256) void queryqk_kernel(
        const short* __restrict__ Wq_bf, const short* __restrict__ tok_t,
        const short* __restrict__ Wk_t, const float* __restrict__ qkb,
        short* __restrict__ qk_bf) {
    __shared__ short q_ld[16 * 64];
    const int t = threadIdx.x, w = t >> 6, L = t & 63;
    const int lr = L & 15, hg = L >> 4;
    const int nh = blockIdx.x, n = nh >> 4, h = nh & 15;

    f32x4 acc = {0.f, 0.f, 0.f, 0.f};
    const short* aA = Wq_bf + (size_t)(h*64 + w*16 + lr) * 1024 + hg*8;
    const short* aB = tok_t + (size_t)n*16384 + (size_t)lr*1024 + hg*8;
#pragma unroll 4
    for (int ks = 0; ks < 32; ++ks) {
        const bf16x8 a = *(const bf16x8*)(aA + ks*32);
        const bf16x8 bb = *(const bf16x8*)(aB + ks*32);
        acc = MFMA16(a, bb, acc);
    }
    {
        bf16x4 qv; qv[0]=f2bf(acc[0]); qv[1]=f2bf(acc[1]); qv[2]=f2bf(acc[2]); qv[3]=f2bf(acc[3]);
        lds_st4(q_ld, (lr*128 + w*32 + hg*8) ^ SWZ(lr), qv);
    }
    __syncthreads();
    f32x4 a2 = {0.f, 0.f, 0.f, 0.f};
#pragma unroll
    for (int ks = 0; ks < 2; ++ks) {
        const bf16x8 a = *(const bf16x8*)(Wk_t + (size_t)h*4096 + (w*16 + lr)*64 + ks*32 + hg*8);
        const bf16x8 bb = lds_ld8(q_ld, (lr*128 + ks*64 + hg*16) ^ SWZ(lr));
        a2 = MFMA16(a, bb, a2);
    }
    const int i0 = w*16 + hg*4;
    bf16x4 qk4;
#pragma unroll
    for (int r = 0; r < 4; ++r)
        qk4[r] = f2bf(a2[r] * 0.125f + qkb[h*64 + i0 + r]);
    *(bf16x4*)(qk_bf + (size_t)nh*1024 + lr*64 + i0) = qk4;
}

// ---------------------------------------------------------------------------
// Kernel 2: swapped-operand single-pass attention (R10 structure, PASSED).
// R11 delta: register-pressure fix only. R10 spilled (~92 live vs 64 alloc;
// WRITE_SIZE doubled to 280 MB = spill traffic). Changes:
//   (1) cross-chunk register prefetch REMOVED — 2-blocks/CU TLP is the
//       latency hiding mechanism; that's the experiment.
//   (2) staging split into two 4-row halves: only v[4] live at once.
// Consume-phase live ~52 regs, stage-phase peak ~68.
// ---------------------------------------------------------------------------
__global__ __launch_bounds__(512, 4) void attn_kernel(
        const float* __restrict__ feat, const short* __restrict__ qk_bf,
        const float* __restrict__ Wv, const float* __restrict__ bv,
        float* __restrict__ out0, float* __restrict__ out1) {
    __shared__ __align__(16) short fx[256 * 64];   // 32 KB [x256][i64] pitch 128B ^SWX(x); reused: f32 partial dump
    __shared__ __align__(16) short fi[64 * 256];   // 32 KB [i64][x256] pitch 512B ^SWI(i); reused: wv [d][i]
    __shared__ __align__(16) short p_scr[8 * 640]; // 10 KB per-wave [l16][x32] pitch 80B
    __shared__ __align__(16) short fcn[16 * 64];   // 2 KB [l][i] pitch 128B ^SWL(l)
    __shared__ float red_m[128], red_z[128];       // [w8][l16]

    const int t = threadIdx.x, w = t >> 6, L = t & 63;
    const int lr = L & 15, hg = L >> 4;
    const int nh = blockIdx.x, n = nh >> 4, h = nh & 15;
    const size_t fbase = (size_t)n*1048576 + (size_t)h*65536;

    // A-operand for logits: qk^T rows l
    const bf16x8 qkA0 = *(const bf16x8*)(qk_bf + (size_t)nh*1024 + lr*64 + hg*8);
    const bf16x8 qkA1 = *(const bf16x8*)(qk_bf + (size_t)nh*1024 + lr*64 + 32 + hg*8);

    const int sx = (t & 63) * 4;   // x-local staging base (lane-major: coalesced)
    const int si = (t >> 6) * 8;   // i staging base (8 rows per wave)
    short* p_w = p_scr + w * 640;  // this wave's P scratch

    f32x4 acc_fc[4];
#pragma unroll
    for (int ct = 0; ct < 4; ++ct) acc_fc[ct] = (f32x4){0.f,0.f,0.f,0.f};
    float mrun[4] = {-INFINITY,-INFINITY,-INFINITY,-INFINITY};
    float Zrun[4] = {0.f,0.f,0.f,0.f};

#pragma unroll
    for (int c = 0; c < 4; ++c) {
        // ---- stage phase: load -> out0 + both LDS images, 4 rows at a time ----
#pragma unroll
        for (int half = 0; half < 2; ++half) {
            const int rb = si + half*4;          // first of 4 rows this half
            f32x4 v[4];
#pragma unroll
            for (int k = 0; k < 4; ++k)
                v[k] = *(const f32x4*)(feat + fbase + (size_t)(rb+k)*1024 + c*256 + sx);
            bf16x4 vb[4];
#pragma unroll
            for (int k = 0; k < 4; ++k) {
                vb[k][0]=f2bf(v[k][0]); vb[k][1]=f2bf(v[k][1]);
                vb[k][2]=f2bf(v[k][2]); vb[k][3]=f2bf(v[k][3]);
            }
#pragma unroll
            for (int k = 0; k < 4; ++k) {
                const size_t g = fbase + (size_t)(rb+k)*1024 + c*256 + sx;
                *(f32x4*)(out0 + g) = v[k];                                // passthrough
                lds_st4(fi, ((rb+k)*512 + sx*2) ^ SWI(rb+k), vb[k]);       // [i][x]
            }
#pragma unroll
            for (int j = 0; j < 4; ++j) {                                  // [x][i]
                const int x = sx + j;
#pragma unroll
                for (int kp = 0; kp < 2; ++kp) {
                    const int i2 = rb + 2*kp;
                    bf16x2 pr; pr[0] = vb[2*kp][j]; pr[1] = vb[2*kp+1][j];
                    *(bf16x2*)((char*)fx + ((x*128 + i2*2) ^ SWX(x))) = pr; // full-offset XOR
                }
            }
        }
        __syncthreads();
        // ---- logits: S^T tiles for wave's 32-x window ----
        f32x4 ST0 = {0.f,0.f,0.f,0.f}, ST1 = {0.f,0.f,0.f,0.f};
        {
            const int xb0 = w*32 + lr, xb1 = w*32 + 16 + lr;
            ST0 = MFMA16(qkA0, lds_ld8(fx, (xb0*128 + hg*16)      ^ SWX(xb0)), ST0);
            ST0 = MFMA16(qkA1, lds_ld8(fx, (xb0*128 + 64 + hg*16) ^ SWX(xb0)), ST0);
            ST1 = MFMA16(qkA0, lds_ld8(fx, (xb1*128 + hg*16)      ^ SWX(xb1)), ST1);
            ST1 = MFMA16(qkA1, lds_ld8(fx, (xb1*128 + 64 + hg*16) ^ SWX(xb1)), ST1);
        }
        // ---- per-wave online softmax (rows l = hg*4+r, cols = its 32 x) ----
#pragma unroll
        for (int r = 0; r < 4; ++r) {
            float cm = fmaxf(ST0[r], ST1[r]);
#pragma unroll
            for (int msk = 8; msk >= 1; msk >>= 1)
                cm = fmaxf(cm, __shfl_xor(cm, msk));          // within 16-lane group
            const float mnew = fmaxf(mrun[r], cm);
            const float rs = __expf(mrun[r] - mnew);          // first chunk: 0
            const float p0 = __expf(ST0[r] - mnew);
            const float p1 = __expf(ST1[r] - mnew);
            const int row = (hg*4 + r) * 80;
            *(short*)((char*)p_w + row + lr*2)      = f2bf(p0);
            *(short*)((char*)p_w + row + 32 + lr*2) = f2bf(p1);
            float zc = p0 + p1;
#pragma unroll
            for (int msk = 8; msk >= 1; msk >>= 1)
                zc += __shfl_xor(zc, msk);
            Zrun[r] = Zrun[r] * rs + zc;
            mrun[r] = mnew;
#pragma unroll
            for (int ct = 0; ct < 4; ++ct) acc_fc[ct][r] *= rs;
        }
        // ---- fc^T += P^T @ f  (K = wave's 32 x) ----
        {
            const bf16x8 pA = lds_ld8(p_w, lr*80 + hg*16);
#pragma unroll
            for (int ct = 0; ct < 4; ++ct) {
                const int i = ct*16 + lr;
                const bf16x8 fB = lds_ld8(fi, (i*512 + w*64 + hg*16) ^ SWI(i));
                acc_fc[ct] = MFMA16(pA, fB, acc_fc[ct]);
            }
        }
        __syncthreads();
    }

    // ---- cross-wave merge ----
    if (lr == 0) {
#pragma unroll
        for (int r = 0; r < 4; ++r) {
            red_m[w*16 + hg*4 + r] = mrun[r];
            red_z[w*16 + hg*4 + r] = Zrun[r];
        }
    }
    __syncthreads();
    {   // stage Wv into fi-carve [d][i] (fi dead now); all 512 threads
        const int d = t >> 3, i0 = (t & 7) * 8;
        const f32x4 a = *(const f32x4*)(Wv + (size_t)h*4096 + d*64 + i0);
        const f32x4 b = *(const f32x4*)(Wv + (size_t)h*4096 + d*64 + i0 + 4);
        bf16x8 wb;
        wb[0]=f2bf(a[0]); wb[1]=f2bf(a[1]); wb[2]=f2bf(a[2]); wb[3]=f2bf(a[3]);
        wb[4]=f2bf(b[0]); wb[5]=f2bf(b[1]); wb[6]=f2bf(b[2]); wb[7]=f2bf(b[3]);
        *(bf16x8*)((char*)fi + ((d*128 + i0*2) ^ SWL(d))) = wb;
    }
    {   // rescale own partials by exp(m_w - m_g), dump to fx region (dead)
        float sc[4];
#pragma unroll
        for (int r = 0; r < 4; ++r) {
            const int l = hg*4 + r;
            float m = red_m[l];
#pragma unroll
            for (int wp = 1; wp < 8; ++wp) m = fmaxf(m, red_m[wp*16 + l]);
            sc[r] = __expf(mrun[r] - m);
        }
#pragma unroll
        for (int ct = 0; ct < 4; ++ct) {
#pragma unroll
            for (int r = 0; r < 4; ++r) acc_fc[ct][r] *= sc[r];
            *(f32x4*)((char*)fx + (w*4 + ct)*1024 + L*16) = acc_fc[ct];
        }
    }
    __syncthreads();
    if (w < 4) {   // reduce i-tile w over 8 wave-partials; normalize; -> fcn
        f32x4 s = (f32x4){0.f,0.f,0.f,0.f};
#pragma unroll
        for (int wp = 0; wp < 8; ++wp)
            s += *(const f32x4*)((const char*)fx + (wp*4 + w)*1024 + L*16);
#pragma unroll
        for (int r = 0; r < 4; ++r) {
            const int l = hg*4 + r;
            float m = red_m[l];
#pragma unroll
            for (int wp = 1; wp < 8; ++wp) m = fmaxf(m, red_m[wp*16 + l]);
            float Z = 0.f;
#pragma unroll
            for (int wp = 0; wp < 8; ++wp)
                Z += __expf(red_m[wp*16 + l] - m) * red_z[wp*16 + l];
            *(short*)((char*)fcn + ((l*128 + (w*16 + lr)*2) ^ SWL(l))) = f2bf(s[r] / Z);
        }
    }
    __syncthreads();
    if (w < 4) {   // tok[d][l] = Wv @ fcn + bv; wave w owns d-tile w
        f32x4 acc = (f32x4){0.f,0.f,0.f,0.f};
        const int dm = w*16 + lr;
#pragma unroll
        for (int ks = 0; ks < 2; ++ks) {
            const bf16x8 a = lds_ld8(fi,  (dm*128 + ks*64 + hg*16) ^ SWL(dm));
            const bf16x8 b = lds_ld8(fcn, (lr*128 + ks*64 + hg*16) ^ SWL(lr));
            acc = MFMA16(a, b, acc);
        }
#pragma unroll
        for (int r = 0; r < 4; ++r) {
            const int d = w*16 + hg*4 + r;
            out1[((size_t)n*1024 + h*64 + d)*16 + lr] = acc[r] + bv[h*64 + d];
        }
    }
}

// ---------------------------------------------------------------------------
extern "C" void kernel_launch(void* const* d_in, const int* in_sizes, int n_in,
                              void* d_out, int out_size, void* d_ws, size_t ws_size,
                              hipStream_t stream) {
    const float* feature = (const float*)d_in[0];
    const float* token   = (const float*)d_in[1];
    const float* Wq      = (const float*)d_in[2];
    const float* bq      = (const float*)d_in[3];
    const float* Wk      = (const float*)d_in[4];
    // d_in[5] = bk: provably unused (constant along softmax axis)
    const float* Wv      = (const float*)d_in[6];
    const float* bv      = (const float*)d_in[7];

    float* out0 = (float*)d_out;                      // feature passthrough
    float* out1 = out0 + (size_t)NB * 1024 * HW;      // tok [n][c][l]

    short* Wq_bf = (short*)d_ws;                               // 2 MB
    short* tok_t = Wq_bf + (size_t)1024 * 1024;                // 1 MB
    short* Wk_t  = tok_t + (size_t)NB * 16 * 1024;             // 128 KB
    short* qk_bf = Wk_t + (size_t)NHEAD * 64 * 64;             // 1 MB
    float* qkb   = (float*)(qk_bf + (size_t)NB * NHEAD * 1024);// 4 KB

    prep_kernel   <<<dim3(1072), 256, 0, stream>>>(Wq, token, Wk, bq, Wq_bf, tok_t, Wk_t, qkb);
    queryqk_kernel<<<dim3(NB * NHEAD), 256, 0, stream>>>(Wq_bf, tok_t, Wk_t, qkb, qk_bf);
    attn_kernel   <<<dim3(NB * NHEAD), 512, 0, stream>>>(feature, qk_bf, Wv, bv, out0, out1);
}

// Round 12
// 81.325 us; speedup vs baseline: 1.6607x; 1.6561x over previous
//
#include <hip/hip_runtime.h>
#include <math.h>

// Problem constants
#define NB    32
#define NHEAD 16
#define HW    1024

typedef float f32x4  __attribute__((ext_vector_type(4)));
typedef short bf16x2 __attribute__((ext_vector_type(2)));
typedef short bf16x4 __attribute__((ext_vector_type(4)));
typedef short bf16x8 __attribute__((ext_vector_type(8)));

__device__ __forceinline__ short f2bf(float f) {   // fp32 -> bf16 RNE
    union { float f; unsigned u; } c; c.f = f;
    unsigned r = c.u + 0x7FFFu + ((c.u >> 16) & 1u);
    return (short)(r >> 16);
}
#define SWZ(row) ((((row) >> 1) & 7) << 4)   // legacy (queryqk)
#define SWX(x)   ((((x) >> 2) & 7) << 4)     // fx image key
#define SWI(i)   ((((i) & 7)) << 4)          // fi image key
#define SWL(l)   ((((l) & 7)) << 4)          // fcn/wv key
#define MFMA16(a, b, c) __builtin_amdgcn_mfma_f32_16x16x32_bf16(a, b, c, 0, 0, 0)

__device__ __forceinline__ bf16x8 lds_ld8(const short* base, int off) {
    return *(const bf16x8*)((const char*)base + off);
}
__device__ __forceinline__ void lds_st4(short* base, int off, bf16x4 v) {
    *(bf16x4*)((char*)base + off) = v;
}

// ---------------------------------------------------------------------------
// Kernel 0: prep — bf16 casts / transposes / bias fold. (unchanged, passes)
// ---------------------------------------------------------------------------
__global__ __launch_bounds__(256) void prep_kernel(
        const float* __restrict__ Wq, const float* __restrict__ token,
        const float* __restrict__ Wk, const float* __restrict__ bq,
        short* __restrict__ Wq_bf, short* __restrict__ tok_t,
        short* __restrict__ Wk_t, float* __restrict__ qkb) {
    __shared__ float red[256];
    const int b = blockIdx.x, t = threadIdx.x;
    if (b < 1024) {
        const size_t idx = (size_t)b * 1024 + t * 4;
        const f32x4 v = *(const f32x4*)(Wq + idx);
        bf16x4 o; o[0]=f2bf(v[0]); o[1]=f2bf(v[1]); o[2]=f2bf(v[2]); o[3]=f2bf(v[3]);
        *(bf16x4*)(Wq_bf + idx) = o;
    } else if (b < 1056) {
        const int n = b - 1024;
        const int c0 = t * 4;
        float arr[4][16];
#pragma unroll
        for (int ci = 0; ci < 4; ++ci)
#pragma unroll
            for (int lq = 0; lq < 4; ++lq) {
                const f32x4 v = *(const f32x4*)(token + (size_t)n*16384 + (size_t)(c0+ci)*16 + lq*4);
#pragma unroll
                for (int e = 0; e < 4; ++e) arr[ci][lq*4+e] = v[e];
            }
#pragma unroll
        for (int l = 0; l < 16; ++l) {
            bf16x4 o; o[0]=f2bf(arr[0][l]); o[1]=f2bf(arr[1][l]); o[2]=f2bf(arr[2][l]); o[3]=f2bf(arr[3][l]);
            *(bf16x4*)(tok_t + (size_t)n*16384 + (size_t)l*1024 + c0) = o;
        }
    } else {
        const int h = b - 1056;
        const int i = t & 63, dq = t >> 6;
        float qs = 0.f; short wt[16];
#pragma unroll
        for (int k = 0; k < 16; ++k) {
            const int d = dq*16 + k;
            const float wv = Wk[(size_t)h*4096 + d*64 + i];
            qs += wv * bq[h*64 + d];
            wt[k] = f2bf(wv);
        }
#pragma unroll
        for (int kq = 0; kq < 4; ++kq) {
            bf16x4 o; o[0]=wt[kq*4]; o[1]=wt[kq*4+1]; o[2]=wt[kq*4+2]; o[3]=wt[kq*4+3];
            *(bf16x4*)(Wk_t + (size_t)h*4096 + i*64 + dq*16 + kq*4) = o;
        }
        red[t] = qs;
        __syncthreads();
        if (t < 64)
            qkb[h*64 + t] = (red[t] + red[t+64] + red[t+128] + red[t+192]) * 0.125f;
    }
}

// ---------------------------------------------------------------------------
// Kernel 1: fused query + qk (all-MFMA). (unchanged, passes)
// ---------------------------------------------------------------------------
__global__ __launch_bounds__(256) void queryqk_kernel(
        const short* __restrict__ Wq_bf, const short* __restrict__ tok_t,
        const short* __restrict__ Wk_t, const float* __restrict__ qkb,
        short* __restrict__ qk_bf) {
    __shared__ short q_ld[16 * 64];
    const int t = threadIdx.x, w = t >> 6, L = t & 63;
    const int lr = L & 15, hg = L >> 4;
    const int nh = blockIdx.x, n = nh >> 4, h = nh & 15;

    f32x4 acc = {0.f, 0.f, 0.f, 0.f};
    const short* aA = Wq_bf + (size_t)(h*64 + w*16 + lr) * 1024 + hg*8;
    const short* aB = tok_t + (size_t)n*16384 + (size_t)lr*1024 + hg*8;
#pragma unroll 4
    for (int ks = 0; ks < 32; ++ks) {
        const bf16x8 a = *(const bf16x8*)(aA + ks*32);
        const bf16x8 bb = *(const bf16x8*)(aB + ks*32);
        acc = MFMA16(a, bb, acc);
    }
    {
        bf16x4 qv; qv[0]=f2bf(acc[0]); qv[1]=f2bf(acc[1]); qv[2]=f2bf(acc[2]); qv[3]=f2bf(acc[3]);
        lds_st4(q_ld, (lr*128 + w*32 + hg*8) ^ SWZ(lr), qv);
    }
    __syncthreads();
    f32x4 a2 = {0.f, 0.f, 0.f, 0.f};
#pragma unroll
    for (int ks = 0; ks < 2; ++ks) {
        const bf16x8 a = *(const bf16x8*)(Wk_t + (size_t)h*4096 + (w*16 + lr)*64 + ks*32 + hg*8);
        const bf16x8 bb = lds_ld8(q_ld, (lr*128 + ks*64 + hg*16) ^ SWZ(lr));
        a2 = MFMA16(a, bb, a2);
    }
    const int i0 = w*16 + hg*4;
    bf16x4 qk4;
#pragma unroll
    for (int r = 0; r < 4; ++r)
        qk4[r] = f2bf(a2[r] * 0.125f + qkb[h*64 + i0 + r]);
    *(bf16x4*)(qk_bf + (size_t)nh*1024 + lr*64 + i0) = qk4;
}

// ---------------------------------------------------------------------------
// Kernel 2: swapped-operand single-pass attention (R10/R11 structure, PASSES).
// R12 delta: `#pragma unroll 1` on the chunk loop. R11's `#pragma unroll`
// fully unrolled 4 chunks; the compiler then hoisted feat loads across
// iterations (loads move over barriers for __restrict readonly data),
// recreating R10's prefetch live-set and spilling it (WRITE_SIZE 2x = 267 MB,
// 133 spilled dwords/thread). unroll 1 pins live range to one chunk (~55
// regs) -> fits the 64-VGPR allocation spill-free. 2 blocks/CU co-residency
// (78.8 KB LDS) provides the latency hiding.
// ---------------------------------------------------------------------------
__global__ __launch_bounds__(512, 4) void attn_kernel(
        const float* __restrict__ feat, const short* __restrict__ qk_bf,
        const float* __restrict__ Wv, const float* __restrict__ bv,
        float* __restrict__ out0, float* __restrict__ out1) {
    __shared__ __align__(16) short fx[256 * 64];   // 32 KB [x256][i64] pitch 128B ^SWX(x); reused: f32 partial dump
    __shared__ __align__(16) short fi[64 * 256];   // 32 KB [i64][x256] pitch 512B ^SWI(i); reused: wv [d][i]
    __shared__ __align__(16) short p_scr[8 * 640]; // 10 KB per-wave [l16][x32] pitch 80B
    __shared__ __align__(16) short fcn[16 * 64];   // 2 KB [l][i] pitch 128B ^SWL(l)
    __shared__ float red_m[128], red_z[128];       // [w8][l16]

    const int t = threadIdx.x, w = t >> 6, L = t & 63;
    const int lr = L & 15, hg = L >> 4;
    const int nh = blockIdx.x, n = nh >> 4, h = nh & 15;
    const size_t fbase = (size_t)n*1048576 + (size_t)h*65536;

    // A-operand for logits: qk^T rows l
    const bf16x8 qkA0 = *(const bf16x8*)(qk_bf + (size_t)nh*1024 + lr*64 + hg*8);
    const bf16x8 qkA1 = *(const bf16x8*)(qk_bf + (size_t)nh*1024 + lr*64 + 32 + hg*8);

    const int sx = (t & 63) * 4;   // x-local staging base (lane-major: coalesced)
    const int si = (t >> 6) * 8;   // i staging base (8 rows per wave)
    short* p_w = p_scr + w * 640;  // this wave's P scratch

    f32x4 acc_fc[4];
#pragma unroll
    for (int ct = 0; ct < 4; ++ct) acc_fc[ct] = (f32x4){0.f,0.f,0.f,0.f};
    float mrun[4] = {-INFINITY,-INFINITY,-INFINITY,-INFINITY};
    float Zrun[4] = {0.f,0.f,0.f,0.f};

#pragma unroll 1   // R12: do NOT unroll — prevents cross-chunk load hoisting + spills
    for (int c = 0; c < 4; ++c) {
        // ---- stage phase: load -> out0 + both LDS images, 4 rows at a time ----
#pragma unroll
        for (int half = 0; half < 2; ++half) {
            const int rb = si + half*4;          // first of 4 rows this half
            f32x4 v[4];
#pragma unroll
            for (int k = 0; k < 4; ++k)
                v[k] = *(const f32x4*)(feat + fbase + (size_t)(rb+k)*1024 + c*256 + sx);
            bf16x4 vb[4];
#pragma unroll
            for (int k = 0; k < 4; ++k) {
                vb[k][0]=f2bf(v[k][0]); vb[k][1]=f2bf(v[k][1]);
                vb[k][2]=f2bf(v[k][2]); vb[k][3]=f2bf(v[k][3]);
            }
#pragma unroll
            for (int k = 0; k < 4; ++k) {
                const size_t g = fbase + (size_t)(rb+k)*1024 + c*256 + sx;
                *(f32x4*)(out0 + g) = v[k];                                // passthrough
                lds_st4(fi, ((rb+k)*512 + sx*2) ^ SWI(rb+k), vb[k]);       // [i][x]
            }
#pragma unroll
            for (int j = 0; j < 4; ++j) {                                  // [x][i]
                const int x = sx + j;
#pragma unroll
                for (int kp = 0; kp < 2; ++kp) {
                    const int i2 = rb + 2*kp;
                    bf16x2 pr; pr[0] = vb[2*kp][j]; pr[1] = vb[2*kp+1][j];
                    *(bf16x2*)((char*)fx + ((x*128 + i2*2) ^ SWX(x))) = pr; // full-offset XOR
                }
            }
        }
        __syncthreads();
        // ---- logits: S^T tiles for wave's 32-x window ----
        f32x4 ST0 = {0.f,0.f,0.f,0.f}, ST1 = {0.f,0.f,0.f,0.f};
        {
            const int xb0 = w*32 + lr, xb1 = w*32 + 16 + lr;
            ST0 = MFMA16(qkA0, lds_ld8(fx, (xb0*128 + hg*16)      ^ SWX(xb0)), ST0);
            ST0 = MFMA16(qkA1, lds_ld8(fx, (xb0*128 + 64 + hg*16) ^ SWX(xb0)), ST0);
            ST1 = MFMA16(qkA0, lds_ld8(fx, (xb1*128 + hg*16)      ^ SWX(xb1)), ST1);
            ST1 = MFMA16(qkA1, lds_ld8(fx, (xb1*128 + 64 + hg*16) ^ SWX(xb1)), ST1);
        }
        // ---- per-wave online softmax (rows l = hg*4+r, cols = its 32 x) ----
#pragma unroll
        for (int r = 0; r < 4; ++r) {
            float cm = fmaxf(ST0[r], ST1[r]);
#pragma unroll
            for (int msk = 8; msk >= 1; msk >>= 1)
                cm = fmaxf(cm, __shfl_xor(cm, msk));          // within 16-lane group
            const float mnew = fmaxf(mrun[r], cm);
            const float rs = __expf(mrun[r] - mnew);          // first chunk: 0
            const float p0 = __expf(ST0[r] - mnew);
            const float p1 = __expf(ST1[r] - mnew);
            const int row = (hg*4 + r) * 80;
            *(short*)((char*)p_w + row + lr*2)      = f2bf(p0);
            *(short*)((char*)p_w + row + 32 + lr*2) = f2bf(p1);
            float zc = p0 + p1;
#pragma unroll
            for (int msk = 8; msk >= 1; msk >>= 1)
                zc += __shfl_xor(zc, msk);
            Zrun[r] = Zrun[r] * rs + zc;
            mrun[r] = mnew;
#pragma unroll
            for (int ct = 0; ct < 4; ++ct) acc_fc[ct][r] *= rs;
        }
        // ---- fc^T += P^T @ f  (K = wave's 32 x) ----
        {
            const bf16x8 pA = lds_ld8(p_w, lr*80 + hg*16);
#pragma unroll
            for (int ct = 0; ct < 4; ++ct) {
                const int i = ct*16 + lr;
                const bf16x8 fB = lds_ld8(fi, (i*512 + w*64 + hg*16) ^ SWI(i));
                acc_fc[ct] = MFMA16(pA, fB, acc_fc[ct]);
            }
        }
        __syncthreads();
    }

    // ---- cross-wave merge ----
    if (lr == 0) {
#pragma unroll
        for (int r = 0; r < 4; ++r) {
            red_m[w*16 + hg*4 + r] = mrun[r];
            red_z[w*16 + hg*4 + r] = Zrun[r];
        }
    }
    __syncthreads();
    {   // stage Wv into fi-carve [d][i] (fi dead now); all 512 threads
        const int d = t >> 3, i0 = (t & 7) * 8;
        const f32x4 a = *(const f32x4*)(Wv + (size_t)h*4096 + d*64 + i0);
        const f32x4 b = *(const f32x4*)(Wv + (size_t)h*4096 + d*64 + i0 + 4);
        bf16x8 wb;
        wb[0]=f2bf(a[0]); wb[1]=f2bf(a[1]); wb[2]=f2bf(a[2]); wb[3]=f2bf(a[3]);
        wb[4]=f2bf(b[0]); wb[5]=f2bf(b[1]); wb[6]=f2bf(b[2]); wb[7]=f2bf(b[3]);
        *(bf16x8*)((char*)fi + ((d*128 + i0*2) ^ SWL(d))) = wb;
    }
    {   // rescale own partials by exp(m_w - m_g), dump to fx region (dead)
        float sc[4];
#pragma unroll
        for (int r = 0; r < 4; ++r) {
            const int l = hg*4 + r;
            float m = red_m[l];
#pragma unroll
            for (int wp = 1; wp < 8; ++wp) m = fmaxf(m, red_m[wp*16 + l]);
            sc[r] = __expf(mrun[r] - m);
        }
#pragma unroll
        for (int ct = 0; ct < 4; ++ct) {
#pragma unroll
            for (int r = 0; r < 4; ++r) acc_fc[ct][r] *= sc[r];
            *(f32x4*)((char*)fx + (w*4 + ct)*1024 + L*16) = acc_fc[ct];
        }
    }
    __syncthreads();
    if (w < 4) {   // reduce i-tile w over 8 wave-partials; normalize; -> fcn
        f32x4 s = (f32x4){0.f,0.f,0.f,0.f};
#pragma unroll
        for (int wp = 0; wp < 8; ++wp)
            s += *(const f32x4*)((const char*)fx + (wp*4 + w)*1024 + L*16);
#pragma unroll
        for (int r = 0; r < 4; ++r) {
            const int l = hg*4 + r;
            float m = red_m[l];
#pragma unroll
            for (int wp = 1; wp < 8; ++wp) m = fmaxf(m, red_m[wp*16 + l]);
            float Z = 0.f;
#pragma unroll
            for (int wp = 0; wp < 8; ++wp)
                Z += __expf(red_m[wp*16 + l] - m) * red_z[wp*16 + l];
            *(short*)((char*)fcn + ((l*128 + (w*16 + lr)*2) ^ SWL(l))) = f2bf(s[r] / Z);
        }
    }
    __syncthreads();
    if (w < 4) {   // tok[d][l] = Wv @ fcn + bv; wave w owns d-tile w
        f32x4 acc = (f32x4){0.f,0.f,0.f,0.f};
        const int dm = w*16 + lr;
#pragma unroll
        for (int ks = 0; ks < 2; ++ks) {
            const bf16x8 a = lds_ld8(fi,  (dm*128 + ks*64 + hg*16) ^ SWL(dm));
            const bf16x8 b = lds_ld8(fcn, (lr*128 + ks*64 + hg*16) ^ SWL(lr));
            acc = MFMA16(a, b, acc);
        }
#pragma unroll
        for (int r = 0; r < 4; ++r) {
            const int d = w*16 + hg*4 + r;
            out1[((size_t)n*1024 + h*64 + d)*16 + lr] = acc[r] + bv[h*64 + d];
        }
    }
}

// ---------------------------------------------------------------------------
extern "C" void kernel_launch(void* const* d_in, const int* in_sizes, int n_in,
                              void* d_out, int out_size, void* d_ws, size_t ws_size,
                              hipStream_t stream) {
    const float* feature = (const float*)d_in[0];
    const float* token   = (const float*)d_in[1];
    const float* Wq      = (const float*)d_in[2];
    const float* bq      = (const float*)d_in[3];
    const float* Wk      = (const float*)d_in[4];
    // d_in[5] = bk: provably unused (constant along softmax axis)
    const float* Wv      = (const float*)d_in[6];
    const float* bv      = (const float*)d_in[7];

    float* out0 = (float*)d_out;                      // feature passthrough
    float* out1 = out0 + (size_t)NB * 1024 * HW;      // tok [n][c][l]

    short* Wq_bf = (short*)d_ws;                               // 2 MB
    short* tok_t = Wq_bf + (size_t)1024 * 1024;                // 1 MB
    short* Wk_t  = tok_t + (size_t)NB * 16 * 1024;             // 128 KB
    short* qk_bf = Wk_t + (size_t)NHEAD * 64 * 64;             // 1 MB
    float* qkb   = (float*)(qk_bf + (size_t)NB * NHEAD * 1024);// 4 KB

    prep_kernel   <<<dim3(1072), 256, 0, stream>>>(Wq, token, Wk, bq, Wq_bf, tok_t, Wk_t, qkb);
    queryqk_kernel<<<dim3(NB * NHEAD), 256, 0, stream>>>(Wq_bf, tok_t, Wk_t, qkb, qk_bf);
    attn_kernel   <<<dim3(NB * NHEAD), 512, 0, stream>>>(feature, qk_bf, Wv, bv, out0, out1);
}